// Round 9
// baseline (671.421 us; speedup 1.0000x reference)
//
#include <hip/hip_runtime.h>

// GAT forward. Pipeline (no global atomics anywhere):
//   fused:   node_transform (h=x@W1, a=h·Wp[:64], b=h·Wp[64:])  ||  pass1:
//            per-block LDS histogram of dst>>7 into count matrix C[g][bin]
//   colscan: per-bin exclusive prefix over blocks (in-place), bin sums S
//   binscan: exclusive scan of S -> binStart
//   pass2:   re-read edges, num=exp(lrelu(a[dst]+b[src]+bp)), write
//            {dl<<17|src, num} to exact slot binStart[bin]+C[g][bin]+ldsCur
//   denomhh: per-bin LDS accumulate denom[128]; hh = h/denom as bf16 packed
//            into first half of the fp32 h row (in place)
//   aggregate: per-bin LDS acc[128][64]; out = sum num*hh[src] + bias
// (alpha denominator gathered at SRC per the reference's quirk.)

#define MAXB 1024          // max dst bins (N/128); 782 for N=100000
#define EPB 4096           // edges per pass1/pass2 block

static __device__ __forceinline__ float bf2f(unsigned short u) {
    unsigned v = (unsigned)u << 16;
    return __builtin_bit_cast(float, v);
}
static __device__ __forceinline__ unsigned short f2bf(float f) {
    unsigned u = __builtin_bit_cast(unsigned, f);
    u = (u + 0x7FFFu + ((u >> 16) & 1u)) >> 16;   // round-to-nearest-even
    return (unsigned short)u;
}

// ---------------- fused: pass1 histogram (blocks [0,G)) + node transform ----
__global__ __launch_bounds__(256) void fused_nt_count_kernel(
    const float* __restrict__ x, const float* __restrict__ W1,
    const float* __restrict__ Wp, const int* __restrict__ ei,
    float* __restrict__ h, float* __restrict__ aArr, float* __restrict__ bArr,
    int* __restrict__ C, int N, int E, int G, int B)
{
    __shared__ float sW1t[64 * 132];   // NT: [o][k], 33 KB
    __shared__ int   cnt[MAXB];        // pass1: 4 KB
    const int tid = threadIdx.x;

    if (blockIdx.x < G) {
        // ---- pass1: count dst bins for edge range [g*EPB, g*EPB+EPB) ----
        const int g = blockIdx.x;
        for (int i = tid; i < B; i += 256) cnt[i] = 0;
        __syncthreads();
        const int base = g * EPB;
        #pragma unroll
        for (int k = 0; k < EPB / 256; ++k) {
            int e = base + k * 256 + tid;
            if (e < E) atomicAdd(&cnt[ei[E + e] >> 7], 1);
        }
        __syncthreads();
        for (int i = tid; i < B; i += 256) C[(size_t)g * B + i] = cnt[i];
        return;
    }

    // ---- node transform: 16 nodes/block, 4 waves, 4 nodes/wave ----
    const int w = tid >> 6, lane = tid & 63;
    for (int i = tid; i < 128 * 64; i += 256)
        sW1t[(i & 63) * 132 + (i >> 6)] = W1[i];

    const float wpa = Wp[lane];
    const float wpb = Wp[64 + lane];
    __syncthreads();

    const int n0 = __builtin_amdgcn_readfirstlane((blockIdx.x - G) * 16 + w * 4);
    const float* xp0 = x + (size_t)n0 * 128;

    float acc[4] = {0.f, 0.f, 0.f, 0.f};
    #pragma unroll 4
    for (int k4 = 0; k4 < 32; ++k4) {
        float4 wv = *reinterpret_cast<const float4*>(&sW1t[lane * 132 + k4 * 4]);
        #pragma unroll
        for (int m = 0; m < 4; ++m) {
            float4 xv = *reinterpret_cast<const float4*>(xp0 + m * 128 + k4 * 4);
            acc[m] = fmaf(xv.x, wv.x, acc[m]);
            acc[m] = fmaf(xv.y, wv.y, acc[m]);
            acc[m] = fmaf(xv.z, wv.z, acc[m]);
            acc[m] = fmaf(xv.w, wv.w, acc[m]);
        }
    }

    #pragma unroll
    for (int m = 0; m < 4; ++m) {
        const int n = n0 + m;
        h[(size_t)n * 64 + lane] = acc[m];
        float a = acc[m] * wpa, b = acc[m] * wpb;
        #pragma unroll
        for (int off = 32; off; off >>= 1) {
            a += __shfl_down(a, off);
            b += __shfl_down(b, off);
        }
        if (lane == 0) { aArr[n] = a; bArr[n] = b; }
    }
}

// ---- colscan: one block per bin; exclusive prefix over blocks, in place ----
__global__ __launch_bounds__(256) void colscan_kernel(
    int* __restrict__ C, int* __restrict__ S, int G, int B)
{
    __shared__ int s[256];
    const int b = blockIdx.x, t = threadIdx.x;
    int g0 = 2 * t, g1 = 2 * t + 1;
    int c0 = (g0 < G) ? C[(size_t)g0 * B + b] : 0;
    int c1 = (g1 < G) ? C[(size_t)g1 * B + b] : 0;
    int v = c0 + c1;
    s[t] = v;
    __syncthreads();
    for (int off = 1; off < 256; off <<= 1) {
        int u = (t >= off) ? s[t - off] : 0;
        __syncthreads();
        s[t] += u;
        __syncthreads();
    }
    int ex = s[t] - v;
    if (g0 < G) C[(size_t)g0 * B + b] = ex;
    if (g1 < G) C[(size_t)g1 * B + b] = ex + c0;
    if (t == 255) S[b] = s[255];
}

// ---- binscan: exclusive scan of S[B] -> binStart[B+1] (1 block) ----
__global__ __launch_bounds__(256) void binscan_kernel(
    const int* __restrict__ S, int* __restrict__ binStart, int B, int E)
{
    __shared__ int ts[256];
    const int t = threadIdx.x;
    const int chunk = (B + 255) >> 8;
    const int base = t * chunk, lim = min(B, base + chunk);
    int s = 0;
    for (int i = base; i < lim; ++i) s += S[i];
    ts[t] = s;
    __syncthreads();
    for (int off = 1; off < 256; off <<= 1) {
        int u = (t >= off) ? ts[t - off] : 0;
        __syncthreads();
        ts[t] += u;
        __syncthreads();
    }
    int run = ts[t] - s;
    for (int i = base; i < lim; ++i) { binStart[i] = run; run += S[i]; }
    if (t == 0) binStart[B] = E;
}

// ---- pass2: deterministic multisplit scatter (LDS cursors, no glb atomics) --
__global__ __launch_bounds__(256) void pass2_kernel(
    const int* __restrict__ ei, const float* __restrict__ aArr,
    const float* __restrict__ bArr, const float* __restrict__ bp,
    const int* __restrict__ C, const int* __restrict__ binStart,
    int2* __restrict__ staging, int E, int G, int B)
{
    __shared__ int cur[MAXB];
    const int g = blockIdx.x, t = threadIdx.x;
    for (int i = t; i < B; i += 256)
        cur[i] = binStart[i] + C[(size_t)g * B + i];
    __syncthreads();
    const float bp0 = bp[0];
    const int base = g * EPB;
    #pragma unroll
    for (int k = 0; k < EPB / 256; ++k) {
        int e = base + k * 256 + t;
        if (e >= E) break;
        int src = ei[e];
        int dst = ei[E + e];
        float s = aArr[dst] + bArr[src] + bp0;
        s = (s >= 0.f) ? s : 0.2f * s;
        float num = __expf(s);
        int bin = dst >> 7;
        int pos = atomicAdd(&cur[bin], 1);   // LDS atomic
        staging[pos] = make_int2(((dst & 127) << 17) | src, __float_as_int(num));
    }
}

// ---- denomhh: per-bin denom via LDS float atomics; hh=h/denom as bf16 ------
__global__ __launch_bounds__(256) void denomhh_kernel(
    const int* __restrict__ binStart, const int2* __restrict__ staging,
    float* __restrict__ h, int N)
{
    __shared__ float dacc[128];
    const int b = blockIdx.x, t = threadIdx.x;
    if (t < 128) dacc[t] = 0.f;
    __syncthreads();
    const int beg = binStart[b], end = binStart[b + 1];
    for (int i = beg + t; i < end; i += 256) {
        int2 p = staging[i];
        atomicAdd(&dacc[p.x >> 17], __int_as_float(p.y));
    }
    __syncthreads();
    const int n0 = b << 7;
    const int Cl = min(128, N - n0);
    // wave w handles one row per iteration (i>>6 constant within wave):
    // fp32 read then bf16 write to the same row is same-wave ordered -> safe.
    for (int i = t; i < Cl * 64; i += 256) {
        int dl = i >> 6, ch = i & 63;
        int n = n0 + dl;
        float inv = 1.f / (dacc[dl] + 1e-16f);
        float hv = h[(size_t)n * 64 + ch];
        reinterpret_cast<unsigned short*>(h)[(size_t)n * 128 + ch] = f2bf(hv * inv);
    }
}

// ---- aggregate: per-bin LDS accumulator, lane = channel --------------------
__global__ __launch_bounds__(256) void aggregate_kernel(
    const int* __restrict__ binStart, const int2* __restrict__ staging,
    const unsigned short* __restrict__ hhB, const float* __restrict__ bias,
    float* __restrict__ out, int N)
{
    __shared__ float acc[128][64];   // 32 KB
    const int b = blockIdx.x, t = threadIdx.x;
    float* accf = &acc[0][0];
    for (int i = t; i < 128 * 64; i += 256) accf[i] = 0.f;
    __syncthreads();

    const int beg = binStart[b], end = binStart[b + 1];
    const int lane = t & 63, wv = t >> 6;
    for (int c = beg + wv * 64; c < end; c += 256) {
        int idx = c + lane;
        int2 p = (idx < end) ? staging[idx] : make_int2(0, 0);
        int cnt = min(64, end - c);
        int j = 0;
        for (; j + 4 <= cnt; j += 4) {
            int dls[4]; float vals[4];
            #pragma unroll
            for (int u = 0; u < 4; ++u) {
                int pk = __shfl(p.x, j + u);
                float wk = __shfl(__int_as_float(p.y), j + u);
                int s = pk & 0x1FFFF;
                dls[u] = pk >> 17;
                vals[u] = bf2f(hhB[(size_t)s * 128 + lane]) * wk;
            }
            #pragma unroll
            for (int u = 0; u < 4; ++u)
                atomicAdd(&acc[dls[u]][lane], vals[u]);
        }
        for (; j < cnt; ++j) {
            int pk = __shfl(p.x, j);
            float wk = __shfl(__int_as_float(p.y), j);
            int s = pk & 0x1FFFF;
            atomicAdd(&acc[pk >> 17][lane], bf2f(hhB[(size_t)s * 128 + lane]) * wk);
        }
    }
    __syncthreads();

    const int n0 = b << 7;
    const int Cl = min(128, N - n0);
    for (int i = t; i < Cl * 64; i += 256) {
        int dl = i >> 6, ch = i & 63;
        out[(size_t)(n0 + dl) * 64 + ch] = acc[dl][ch] + bias[ch];
    }
}

extern "C" void kernel_launch(void* const* d_in, const int* in_sizes, int n_in,
                              void* d_out, int out_size, void* d_ws, size_t ws_size,
                              hipStream_t stream) {
    const float* x    = (const float*)d_in[0];
    const int*   ei   = (const int*)d_in[1];
    // d_in[2] = rank_mapping (unused)
    const float* W1   = (const float*)d_in[3];
    const float* Wp   = (const float*)d_in[4];
    const float* bp   = (const float*)d_in[5];
    const float* bias = (const float*)d_in[6];
    float* out = (float*)d_out;

    const int N = in_sizes[0] / 128;
    const int E = in_sizes[1] / 2;
    const int B = (N + 127) >> 7;        // dst bins of 128 nodes (782)
    const int G = (E + EPB - 1) / EPB;   // pass1/pass2 blocks (306)
    const int NTB = (N + 15) / 16;       // node-transform blocks (6250)

    // workspace (4B units):
    // h[N*64] | a[N] | b[N] | C[G*B] | S[B] | binStart[B+1] | staging[E] int2
    float* h        = (float*)d_ws;
    float* aArr     = h + (size_t)N * 64;
    float* bArr     = aArr + N;
    int*   C        = (int*)(bArr + N);
    int*   S        = C + (size_t)G * B;
    int*   binStart = S + B;
    int*   stRaw    = binStart + (B + 1);
    stRaw = (int*)(((uintptr_t)stRaw + 7) & ~(uintptr_t)7);
    int2*  staging  = (int2*)stRaw;

    // pass1 blocks FIRST so they dispatch early and overlap node transform.
    fused_nt_count_kernel<<<G + NTB, 256, 0, stream>>>(
        x, W1, Wp, ei, h, aArr, bArr, C, N, E, G, B);

    colscan_kernel<<<B, 256, 0, stream>>>(C, S, G, B);

    binscan_kernel<<<1, 256, 0, stream>>>(S, binStart, B, E);

    pass2_kernel<<<G, 256, 0, stream>>>(ei, aArr, bArr, bp, C, binStart,
                                        staging, E, G, B);

    denomhh_kernel<<<B, 256, 0, stream>>>(binStart, staging, h, N);

    aggregate_kernel<<<B, 256, 0, stream>>>(
        binStart, staging, reinterpret_cast<const unsigned short*>(h), bias, out, N);
}

// Round 10
// 163.535 us; speedup vs baseline: 4.1057x; 4.1057x over previous
//
#include <hip/hip_runtime.h>

// GAT forward. Atomic-free multisplit sort + wave-per-node consumers.
//   fused:   node_transform (h=x@W1, a=h·Wp[:64], b=h·Wp[64:]) || pass1
//            per-block LDS histogram of dst>>7 into C[g][bin]
//   colscan: per-bin exclusive prefix over blocks (in-place), bin sums S
//   binscan: exclusive scan S -> binStart; offsets[N]=E
//   pass2:   re-read edges, num=exp(lrelu(a[dst]+b[src]+bp)), write
//            {dl<<17|src, num} to exact slot binStart[bin]+C[g][bin]+ldsCur
//   localsort: per bin (782 blocks): LDS counting sort to exact dst order
//            in-place; emits CSR offsets (offsets[n] = sBeg + exscan)
//   denom_hh: wave per node: denom = seg-sum of num; hh = h/denom bf16 packed
//            into first half of fp32 h row (in place)
//   aggregate: wave per node, 2 edges per dword gather of hh, coalesced store
// (alpha denominator gathered at SRC per the reference's quirk.)

#define MAXB 1024          // max dst bins (N/128); 782 for N=100000
#define EPB 4096           // edges per pass1/pass2 block
#define BIN_CAP 2560       // max edges per 128-node bin (mean 1600, sigma 40)

static __device__ __forceinline__ float bf2f(unsigned short u) {
    unsigned v = (unsigned)u << 16;
    return __builtin_bit_cast(float, v);
}
static __device__ __forceinline__ unsigned short f2bf(float f) {
    unsigned u = __builtin_bit_cast(unsigned, f);
    u = (u + 0x7FFFu + ((u >> 16) & 1u)) >> 16;   // round-to-nearest-even
    return (unsigned short)u;
}

// ---------------- fused: pass1 histogram (blocks [0,G)) + node transform ----
__global__ __launch_bounds__(256) void fused_nt_count_kernel(
    const float* __restrict__ x, const float* __restrict__ W1,
    const float* __restrict__ Wp, const int* __restrict__ ei,
    float* __restrict__ h, float* __restrict__ aArr, float* __restrict__ bArr,
    int* __restrict__ C, int N, int E, int G, int B)
{
    __shared__ float sW1t[64 * 132];   // NT: [o][k], 33 KB
    __shared__ int   cnt[MAXB];        // pass1: 4 KB
    const int tid = threadIdx.x;

    if (blockIdx.x < G) {
        const int g = blockIdx.x;
        for (int i = tid; i < B; i += 256) cnt[i] = 0;
        __syncthreads();
        const int base = g * EPB;
        #pragma unroll
        for (int k = 0; k < EPB / 256; ++k) {
            int e = base + k * 256 + tid;
            if (e < E) atomicAdd(&cnt[ei[E + e] >> 7], 1);
        }
        __syncthreads();
        for (int i = tid; i < B; i += 256) C[(size_t)g * B + i] = cnt[i];
        return;
    }

    const int w = tid >> 6, lane = tid & 63;
    for (int i = tid; i < 128 * 64; i += 256)
        sW1t[(i & 63) * 132 + (i >> 6)] = W1[i];

    const float wpa = Wp[lane];
    const float wpb = Wp[64 + lane];
    __syncthreads();

    const int n0 = __builtin_amdgcn_readfirstlane((blockIdx.x - G) * 16 + w * 4);
    const float* xp0 = x + (size_t)n0 * 128;

    float acc[4] = {0.f, 0.f, 0.f, 0.f};
    #pragma unroll 4
    for (int k4 = 0; k4 < 32; ++k4) {
        float4 wv = *reinterpret_cast<const float4*>(&sW1t[lane * 132 + k4 * 4]);
        #pragma unroll
        for (int m = 0; m < 4; ++m) {
            float4 xv = *reinterpret_cast<const float4*>(xp0 + m * 128 + k4 * 4);
            acc[m] = fmaf(xv.x, wv.x, acc[m]);
            acc[m] = fmaf(xv.y, wv.y, acc[m]);
            acc[m] = fmaf(xv.z, wv.z, acc[m]);
            acc[m] = fmaf(xv.w, wv.w, acc[m]);
        }
    }

    #pragma unroll
    for (int m = 0; m < 4; ++m) {
        const int n = n0 + m;
        h[(size_t)n * 64 + lane] = acc[m];
        float a = acc[m] * wpa, b = acc[m] * wpb;
        #pragma unroll
        for (int off = 32; off; off >>= 1) {
            a += __shfl_down(a, off);
            b += __shfl_down(b, off);
        }
        if (lane == 0) { aArr[n] = a; bArr[n] = b; }
    }
}

// ---- colscan: one block per bin; exclusive prefix over blocks, in place ----
__global__ __launch_bounds__(256) void colscan_kernel(
    int* __restrict__ C, int* __restrict__ S, int G, int B)
{
    __shared__ int s[256];
    const int b = blockIdx.x, t = threadIdx.x;
    int g0 = 2 * t, g1 = 2 * t + 1;
    int c0 = (g0 < G) ? C[(size_t)g0 * B + b] : 0;
    int c1 = (g1 < G) ? C[(size_t)g1 * B + b] : 0;
    int v = c0 + c1;
    s[t] = v;
    __syncthreads();
    for (int off = 1; off < 256; off <<= 1) {
        int u = (t >= off) ? s[t - off] : 0;
        __syncthreads();
        s[t] += u;
        __syncthreads();
    }
    int ex = s[t] - v;
    if (g0 < G) C[(size_t)g0 * B + b] = ex;
    if (g1 < G) C[(size_t)g1 * B + b] = ex + c0;
    if (t == 255) S[b] = s[255];
}

// ---- binscan: exclusive scan of S[B] -> binStart[B+1]; offsets[N]=E --------
__global__ __launch_bounds__(256) void binscan_kernel(
    const int* __restrict__ S, int* __restrict__ binStart,
    int* __restrict__ offsets, int B, int N, int E)
{
    __shared__ int ts[256];
    const int t = threadIdx.x;
    const int chunk = (B + 255) >> 8;
    const int base = t * chunk, lim = min(B, base + chunk);
    int s = 0;
    for (int i = base; i < lim; ++i) s += S[i];
    ts[t] = s;
    __syncthreads();
    for (int off = 1; off < 256; off <<= 1) {
        int u = (t >= off) ? ts[t - off] : 0;
        __syncthreads();
        ts[t] += u;
        __syncthreads();
    }
    int run = ts[t] - s;
    for (int i = base; i < lim; ++i) { binStart[i] = run; run += S[i]; }
    if (t == 0) { binStart[B] = E; offsets[N] = E; }
}

// ---- pass2: deterministic multisplit scatter (LDS cursors, no glb atomics) --
__global__ __launch_bounds__(256) void pass2_kernel(
    const int* __restrict__ ei, const float* __restrict__ aArr,
    const float* __restrict__ bArr, const float* __restrict__ bp,
    const int* __restrict__ C, const int* __restrict__ binStart,
    int2* __restrict__ staging, int E, int G, int B)
{
    __shared__ int cur[MAXB];
    const int g = blockIdx.x, t = threadIdx.x;
    for (int i = t; i < B; i += 256)
        cur[i] = binStart[i] + C[(size_t)g * B + i];
    __syncthreads();
    const float bp0 = bp[0];
    const int base = g * EPB;
    #pragma unroll
    for (int k = 0; k < EPB / 256; ++k) {
        int e = base + k * 256 + t;
        if (e >= E) break;
        int src = ei[e];
        int dst = ei[E + e];
        float s = aArr[dst] + bArr[src] + bp0;
        s = (s >= 0.f) ? s : 0.2f * s;
        float num = __expf(s);
        int bin = dst >> 7;
        int pos = atomicAdd(&cur[bin], 1);   // LDS atomic
        staging[pos] = make_int2(((dst & 127) << 17) | src, __float_as_int(num));
    }
}

// ---- localsort: per bin, exact dst order in place + CSR offsets ------------
__global__ __launch_bounds__(256) void localsort_kernel(
    const int* __restrict__ binStart, int2* __restrict__ staging,
    int* __restrict__ offsets, int N)
{
    __shared__ int2 sEnt[BIN_CAP];       // 20 KB
    __shared__ int sCnt[256], sScan[256], sCur[128];
    const int b = blockIdx.x, t = threadIdx.x;
    const int sBeg = binStart[b];
    const int count = min(binStart[b + 1] - sBeg, BIN_CAP);

    sCnt[t] = 0;
    if (t < 128) sCur[t] = 0;
    __syncthreads();
    for (int i = t; i < count; i += 256) {
        int2 e = staging[sBeg + i];
        sEnt[i] = e;
        atomicAdd(&sCnt[e.x >> 17], 1);
    }
    __syncthreads();
    int v = sCnt[t];
    sScan[t] = v;
    __syncthreads();
    for (int off = 1; off < 256; off <<= 1) {
        int u = (t >= off) ? sScan[t - off] : 0;
        __syncthreads();
        sScan[t] += u;
        __syncthreads();
    }
    int ex = sScan[t] - v;
    __syncthreads();
    sScan[t] = ex;                       // exclusive scan in place
    const int n0 = b << 7;
    const int Cl = min(128, N - n0);
    if (t < Cl) offsets[n0 + t] = sBeg + ex;
    __syncthreads();
    for (int i = t; i < count; i += 256) {
        int2 e = sEnt[i];
        int dl = e.x >> 17;
        int pos = sBeg + sScan[dl] + atomicAdd(&sCur[dl], 1);
        staging[pos] = make_int2(e.x & 0x1FFFF, e.y);   // {src, num}
    }
}

// ---------------- denom + hh: wave per node ----------------
__global__ __launch_bounds__(256) void denom_hh_kernel(
    const int* __restrict__ offsets, const int2* __restrict__ sortedPair,
    float* __restrict__ h, int N)
{
    int gw = (blockIdx.x * blockDim.x + threadIdx.x) >> 6;
    int lane = threadIdx.x & 63;
    if (gw >= N) return;
    int beg = offsets[gw], end = offsets[gw + 1];
    float s = 0.f;
    for (int e = beg + lane; e < end; e += 64) s += __int_as_float(sortedPair[e].y);
    #pragma unroll
    for (int off = 32; off; off >>= 1) s += __shfl_down(s, off);
    s = __shfl(s, 0);
    float inv = 1.f / (s + 1e-16f);
    float hv = h[(size_t)gw * 64 + lane];
    asm volatile("" ::: "memory");   // order read-before-aliased-write
    unsigned short* row = reinterpret_cast<unsigned short*>(h) + (size_t)gw * 128;
    row[lane] = f2bf(hv * inv);
}

// ---------------- aggregate: wave per dst node, 2 edges per gather ----------
// hh row = 64 bf16 in the first 32 dwords of a 64-dword fp32 row (base s*64).
__global__ __launch_bounds__(256) void aggregate_kernel(
    const int* __restrict__ offsets, const int2* __restrict__ sortedPair,
    const unsigned* __restrict__ hhW, const float* __restrict__ bias,
    float* __restrict__ out, int N)
{
    int gw = (blockIdx.x * blockDim.x + threadIdx.x) >> 6;
    int lane = threadIdx.x & 63;
    if (gw >= N) return;
    int beg = offsets[gw], end = offsets[gw + 1];
    const int half = lane >> 5;
    const int cp = lane & 31;
    float accx = 0.f, accy = 0.f;
    for (int e0 = beg; e0 < end; e0 += 64) {
        int idx = e0 + lane;
        int2 p = (idx < end) ? sortedPair[idx] : make_int2(0, 0);
        int cnt = min(64, end - e0);
        int j = 0;
        for (; j + 8 <= cnt; j += 8) {
            #pragma unroll
            for (int u = 0; u < 4; ++u) {
                int jj = j + 2 * u + half;
                int s = __shfl(p.x, jj);
                float wv = __shfl(__int_as_float(p.y), jj);
                unsigned g = hhW[(size_t)s * 64 + cp];
                accx = fmaf(bf2f((unsigned short)(g & 0xFFFFu)), wv, accx);
                accy = fmaf(bf2f((unsigned short)(g >> 16)), wv, accy);
            }
        }
        for (; j < cnt; j += 2) {
            int jj = j + half;
            bool v = jj < cnt;
            int s = __shfl(p.x, v ? jj : j);
            float wv = v ? __shfl(__int_as_float(p.y), jj) : 0.f;
            unsigned g = hhW[(size_t)s * 64 + cp];
            accx = fmaf(bf2f((unsigned short)(g & 0xFFFFu)), wv, accx);
            accy = fmaf(bf2f((unsigned short)(g >> 16)), wv, accy);
        }
    }
    accx += __shfl_xor(accx, 32);
    accy += __shfl_xor(accy, 32);
    if (lane < 32) {
        float2 b = reinterpret_cast<const float2*>(bias)[cp];
        float2 o; o.x = accx + b.x; o.y = accy + b.y;
        reinterpret_cast<float2*>(out)[(size_t)gw * 32 + cp] = o;
    }
}

extern "C" void kernel_launch(void* const* d_in, const int* in_sizes, int n_in,
                              void* d_out, int out_size, void* d_ws, size_t ws_size,
                              hipStream_t stream) {
    const float* x    = (const float*)d_in[0];
    const int*   ei   = (const int*)d_in[1];
    // d_in[2] = rank_mapping (unused)
    const float* W1   = (const float*)d_in[3];
    const float* Wp   = (const float*)d_in[4];
    const float* bp   = (const float*)d_in[5];
    const float* bias = (const float*)d_in[6];
    float* out = (float*)d_out;

    const int N = in_sizes[0] / 128;
    const int E = in_sizes[1] / 2;
    const int B = (N + 127) >> 7;        // dst bins of 128 nodes (782)
    const int G = (E + EPB - 1) / EPB;   // pass1/pass2 blocks (306)
    const int NTB = (N + 15) / 16;       // node-transform blocks (6250)

    // workspace (4B units):
    // h[N*64] | a[N] | b[N] | C[G*B] | S[B] | binStart[B+1] | offsets[N+1] |
    // staging[E] int2
    float* h        = (float*)d_ws;
    float* aArr     = h + (size_t)N * 64;
    float* bArr     = aArr + N;
    int*   C        = (int*)(bArr + N);
    int*   S        = C + (size_t)G * B;
    int*   binStart = S + B;
    int*   offsets  = binStart + (B + 1);
    int*   stRaw    = offsets + (N + 1);
    stRaw = (int*)(((uintptr_t)stRaw + 7) & ~(uintptr_t)7);
    int2*  staging  = (int2*)stRaw;

    // pass1 blocks FIRST so they dispatch early and overlap node transform.
    fused_nt_count_kernel<<<G + NTB, 256, 0, stream>>>(
        x, W1, Wp, ei, h, aArr, bArr, C, N, E, G, B);

    colscan_kernel<<<B, 256, 0, stream>>>(C, S, G, B);

    binscan_kernel<<<1, 256, 0, stream>>>(S, binStart, offsets, B, N, E);

    pass2_kernel<<<G, 256, 0, stream>>>(ei, aArr, bArr, bp, C, binStart,
                                        staging, E, G, B);

    localsort_kernel<<<B, 256, 0, stream>>>(binStart, staging, offsets, N);

    denom_hh_kernel<<<(N * 64 + 255) / 256, 256, 0, stream>>>(offsets, staging, h, N);

    aggregate_kernel<<<(N * 64 + 255) / 256, 256, 0, stream>>>(
        offsets, staging, reinterpret_cast<const unsigned*>(h), bias, out, N);
}

// Round 11
// 163.254 us; speedup vs baseline: 4.1127x; 1.0017x over previous
//
#include <hip/hip_runtime.h>

// GAT forward. Atomic-free multisplit sort + wave-per-node consumers.
//   fused:   node_transform (h=x@W1, a=h·Wp[:64], b=h·Wp[64:]) || pass1
//            per-block LDS histogram of dst>>7 into C[g][bin]
//   colscan: per-bin exclusive prefix over blocks (in-place), bin sums S
//   binscan: exclusive scan S -> binStart; offsets[N]=E
//   pass2:   re-read edges, num=exp(lrelu(a[dst]+b[src]+bp)), write
//            {dl<<17|src, num} to exact slot binStart[bin]+C[g][bin]+ldsCur
//   localsort: per bin: LDS counting sort to exact dst order in-place;
//            emits CSR offsets (offsets[n] = sBeg + exscan)
//   denom_hh: wave per node: denom = seg-sum of num; hh = h/denom bf16 packed
//            into first half of fp32 h row (in place)
//   aggregate: wave per node, 2 edges per dword gather of hh, coalesced store
// (alpha denominator gathered at SRC per the reference's quirk.)
// NT v4: 1024 persistent blocks stage W1 once and grid-stride over groups of
// 32 nodes (4 waves x 8 nodes/wave) — W1 staging amortized ~3x, 2x inner ILP.

#define MAXB 1024          // max dst bins (N/128); 782 for N=100000
#define EPB 4096           // edges per pass1/pass2 block
#define BIN_CAP 2560       // max edges per 128-node bin (mean 1600, sigma 40)
#define NTBLK 1024         // persistent NT blocks

static __device__ __forceinline__ float bf2f(unsigned short u) {
    unsigned v = (unsigned)u << 16;
    return __builtin_bit_cast(float, v);
}
static __device__ __forceinline__ unsigned short f2bf(float f) {
    unsigned u = __builtin_bit_cast(unsigned, f);
    u = (u + 0x7FFFu + ((u >> 16) & 1u)) >> 16;   // round-to-nearest-even
    return (unsigned short)u;
}

// ---------------- fused: pass1 histogram (blocks [0,G)) + node transform ----
__global__ __launch_bounds__(256) void fused_nt_count_kernel(
    const float* __restrict__ x, const float* __restrict__ W1,
    const float* __restrict__ Wp, const int* __restrict__ ei,
    float* __restrict__ h, float* __restrict__ aArr, float* __restrict__ bArr,
    int* __restrict__ C, int N, int E, int G, int B)
{
    __shared__ float sW1t[64 * 132];   // NT: [o][k], 33 KB
    __shared__ int   cnt[MAXB];        // pass1: 4 KB
    const int tid = threadIdx.x;

    if (blockIdx.x < G) {
        const int g = blockIdx.x;
        for (int i = tid; i < B; i += 256) cnt[i] = 0;
        __syncthreads();
        const int base = g * EPB;
        #pragma unroll
        for (int k = 0; k < EPB / 256; ++k) {
            int e = base + k * 256 + tid;
            if (e < E) atomicAdd(&cnt[ei[E + e] >> 7], 1);
        }
        __syncthreads();
        for (int i = tid; i < B; i += 256) C[(size_t)g * B + i] = cnt[i];
        return;
    }

    // ---- node transform: persistent block, grid-stride over 32-node groups
    const int w = tid >> 6, lane = tid & 63;
    for (int i = tid; i < 128 * 64; i += 256)
        sW1t[(i & 63) * 132 + (i >> 6)] = W1[i];

    const float wpa = Wp[lane];
    const float wpb = Wp[64 + lane];
    __syncthreads();

    const int nGroups = (N + 31) / 32;         // 3125
    for (int grp = blockIdx.x - G; grp < nGroups; grp += NTBLK) {
        const int n0 = __builtin_amdgcn_readfirstlane(grp * 32 + w * 8);
        const float* xp0 = x + (size_t)n0 * 128;

        float acc[8] = {0.f, 0.f, 0.f, 0.f, 0.f, 0.f, 0.f, 0.f};
        #pragma unroll 2
        for (int k4 = 0; k4 < 32; ++k4) {
            float4 wv = *reinterpret_cast<const float4*>(&sW1t[lane * 132 + k4 * 4]);
            #pragma unroll
            for (int m = 0; m < 8; ++m) {
                float4 xv = *reinterpret_cast<const float4*>(xp0 + m * 128 + k4 * 4);
                acc[m] = fmaf(xv.x, wv.x, acc[m]);
                acc[m] = fmaf(xv.y, wv.y, acc[m]);
                acc[m] = fmaf(xv.z, wv.z, acc[m]);
                acc[m] = fmaf(xv.w, wv.w, acc[m]);
            }
        }

        #pragma unroll
        for (int m = 0; m < 8; ++m) {
            const int n = n0 + m;
            h[(size_t)n * 64 + lane] = acc[m];
            float a = acc[m] * wpa, b = acc[m] * wpb;
            #pragma unroll
            for (int off = 32; off; off >>= 1) {
                a += __shfl_down(a, off);
                b += __shfl_down(b, off);
            }
            if (lane == 0) { aArr[n] = a; bArr[n] = b; }
        }
    }
}

// ---- colscan: one block per bin; exclusive prefix over blocks, in place ----
__global__ __launch_bounds__(256) void colscan_kernel(
    int* __restrict__ C, int* __restrict__ S, int G, int B)
{
    __shared__ int s[256];
    const int b = blockIdx.x, t = threadIdx.x;
    int g0 = 2 * t, g1 = 2 * t + 1;
    int c0 = (g0 < G) ? C[(size_t)g0 * B + b] : 0;
    int c1 = (g1 < G) ? C[(size_t)g1 * B + b] : 0;
    int v = c0 + c1;
    s[t] = v;
    __syncthreads();
    for (int off = 1; off < 256; off <<= 1) {
        int u = (t >= off) ? s[t - off] : 0;
        __syncthreads();
        s[t] += u;
        __syncthreads();
    }
    int ex = s[t] - v;
    if (g0 < G) C[(size_t)g0 * B + b] = ex;
    if (g1 < G) C[(size_t)g1 * B + b] = ex + c0;
    if (t == 255) S[b] = s[255];
}

// ---- binscan: exclusive scan of S[B] -> binStart[B+1]; offsets[N]=E --------
__global__ __launch_bounds__(256) void binscan_kernel(
    const int* __restrict__ S, int* __restrict__ binStart,
    int* __restrict__ offsets, int B, int N, int E)
{
    __shared__ int ts[256];
    const int t = threadIdx.x;
    const int chunk = (B + 255) >> 8;
    const int base = t * chunk, lim = min(B, base + chunk);
    int s = 0;
    for (int i = base; i < lim; ++i) s += S[i];
    ts[t] = s;
    __syncthreads();
    for (int off = 1; off < 256; off <<= 1) {
        int u = (t >= off) ? ts[t - off] : 0;
        __syncthreads();
        ts[t] += u;
        __syncthreads();
    }
    int run = ts[t] - s;
    for (int i = base; i < lim; ++i) { binStart[i] = run; run += S[i]; }
    if (t == 0) { binStart[B] = E; offsets[N] = E; }
}

// ---- pass2: deterministic multisplit scatter (LDS cursors, no glb atomics) --
__global__ __launch_bounds__(256) void pass2_kernel(
    const int* __restrict__ ei, const float* __restrict__ aArr,
    const float* __restrict__ bArr, const float* __restrict__ bp,
    const int* __restrict__ C, const int* __restrict__ binStart,
    int2* __restrict__ staging, int E, int G, int B)
{
    __shared__ int cur[MAXB];
    const int g = blockIdx.x, t = threadIdx.x;
    for (int i = t; i < B; i += 256)
        cur[i] = binStart[i] + C[(size_t)g * B + i];
    __syncthreads();
    const float bp0 = bp[0];
    const int base = g * EPB;
    #pragma unroll
    for (int k = 0; k < EPB / 256; ++k) {
        int e = base + k * 256 + t;
        if (e >= E) break;
        int src = ei[e];
        int dst = ei[E + e];
        float s = aArr[dst] + bArr[src] + bp0;
        s = (s >= 0.f) ? s : 0.2f * s;
        float num = __expf(s);
        int bin = dst >> 7;
        int pos = atomicAdd(&cur[bin], 1);   // LDS atomic
        staging[pos] = make_int2(((dst & 127) << 17) | src, __float_as_int(num));
    }
}

// ---- localsort: per bin, exact dst order in place + CSR offsets ------------
__global__ __launch_bounds__(256) void localsort_kernel(
    const int* __restrict__ binStart, int2* __restrict__ staging,
    int* __restrict__ offsets, int N)
{
    __shared__ int2 sEnt[BIN_CAP];       // 20 KB
    __shared__ int sCnt[256], sScan[256], sCur[128];
    const int b = blockIdx.x, t = threadIdx.x;
    const int sBeg = binStart[b];
    const int count = min(binStart[b + 1] - sBeg, BIN_CAP);

    sCnt[t] = 0;
    if (t < 128) sCur[t] = 0;
    __syncthreads();
    for (int i = t; i < count; i += 256) {
        int2 e = staging[sBeg + i];
        sEnt[i] = e;
        atomicAdd(&sCnt[e.x >> 17], 1);
    }
    __syncthreads();
    int v = sCnt[t];
    sScan[t] = v;
    __syncthreads();
    for (int off = 1; off < 256; off <<= 1) {
        int u = (t >= off) ? sScan[t - off] : 0;
        __syncthreads();
        sScan[t] += u;
        __syncthreads();
    }
    int ex = sScan[t] - v;
    __syncthreads();
    sScan[t] = ex;                       // exclusive scan in place
    const int n0 = b << 7;
    const int Cl = min(128, N - n0);
    if (t < Cl) offsets[n0 + t] = sBeg + ex;
    __syncthreads();
    for (int i = t; i < count; i += 256) {
        int2 e = sEnt[i];
        int dl = e.x >> 17;
        int pos = sBeg + sScan[dl] + atomicAdd(&sCur[dl], 1);
        staging[pos] = make_int2(e.x & 0x1FFFF, e.y);   // {src, num}
    }
}

// ---------------- denom + hh: wave per node ----------------
__global__ __launch_bounds__(256) void denom_hh_kernel(
    const int* __restrict__ offsets, const int2* __restrict__ sortedPair,
    float* __restrict__ h, int N)
{
    int gw = (blockIdx.x * blockDim.x + threadIdx.x) >> 6;
    int lane = threadIdx.x & 63;
    if (gw >= N) return;
    int beg = offsets[gw], end = offsets[gw + 1];
    float s = 0.f;
    for (int e = beg + lane; e < end; e += 64) s += __int_as_float(sortedPair[e].y);
    #pragma unroll
    for (int off = 32; off; off >>= 1) s += __shfl_down(s, off);
    s = __shfl(s, 0);
    float inv = 1.f / (s + 1e-16f);
    float hv = h[(size_t)gw * 64 + lane];
    asm volatile("" ::: "memory");   // order read-before-aliased-write
    unsigned short* row = reinterpret_cast<unsigned short*>(h) + (size_t)gw * 128;
    row[lane] = f2bf(hv * inv);
}

// ---------------- aggregate: wave per dst node, 2 edges per gather ----------
// hh row = 64 bf16 in the first 32 dwords of a 64-dword fp32 row (base s*64).
__global__ __launch_bounds__(256) void aggregate_kernel(
    const int* __restrict__ offsets, const int2* __restrict__ sortedPair,
    const unsigned* __restrict__ hhW, const float* __restrict__ bias,
    float* __restrict__ out, int N)
{
    int gw = (blockIdx.x * blockDim.x + threadIdx.x) >> 6;
    int lane = threadIdx.x & 63;
    if (gw >= N) return;
    int beg = offsets[gw], end = offsets[gw + 1];
    const int half = lane >> 5;
    const int cp = lane & 31;
    float accx = 0.f, accy = 0.f;
    for (int e0 = beg; e0 < end; e0 += 64) {
        int idx = e0 + lane;
        int2 p = (idx < end) ? sortedPair[idx] : make_int2(0, 0);
        int cnt = min(64, end - e0);
        int j = 0;
        for (; j + 8 <= cnt; j += 8) {
            #pragma unroll
            for (int u = 0; u < 4; ++u) {
                int jj = j + 2 * u + half;
                int s = __shfl(p.x, jj);
                float wv = __shfl(__int_as_float(p.y), jj);
                unsigned g = hhW[(size_t)s * 64 + cp];
                accx = fmaf(bf2f((unsigned short)(g & 0xFFFFu)), wv, accx);
                accy = fmaf(bf2f((unsigned short)(g >> 16)), wv, accy);
            }
        }
        for (; j < cnt; j += 2) {
            int jj = j + half;
            bool v = jj < cnt;
            int s = __shfl(p.x, v ? jj : j);
            float wv = v ? __shfl(__int_as_float(p.y), jj) : 0.f;
            unsigned g = hhW[(size_t)s * 64 + cp];
            accx = fmaf(bf2f((unsigned short)(g & 0xFFFFu)), wv, accx);
            accy = fmaf(bf2f((unsigned short)(g >> 16)), wv, accy);
        }
    }
    accx += __shfl_xor(accx, 32);
    accy += __shfl_xor(accy, 32);
    if (lane < 32) {
        float2 b = reinterpret_cast<const float2*>(bias)[cp];
        float2 o; o.x = accx + b.x; o.y = accy + b.y;
        reinterpret_cast<float2*>(out)[(size_t)gw * 32 + cp] = o;
    }
}

extern "C" void kernel_launch(void* const* d_in, const int* in_sizes, int n_in,
                              void* d_out, int out_size, void* d_ws, size_t ws_size,
                              hipStream_t stream) {
    const float* x    = (const float*)d_in[0];
    const int*   ei   = (const int*)d_in[1];
    // d_in[2] = rank_mapping (unused)
    const float* W1   = (const float*)d_in[3];
    const float* Wp   = (const float*)d_in[4];
    const float* bp   = (const float*)d_in[5];
    const float* bias = (const float*)d_in[6];
    float* out = (float*)d_out;

    const int N = in_sizes[0] / 128;
    const int E = in_sizes[1] / 2;
    const int B = (N + 127) >> 7;        // dst bins of 128 nodes (782)
    const int G = (E + EPB - 1) / EPB;   // pass1/pass2 blocks (306)

    // workspace (4B units):
    // h[N*64] | a[N] | b[N] | C[G*B] | S[B] | binStart[B+1] | offsets[N+1] |
    // staging[E] int2
    float* h        = (float*)d_ws;
    float* aArr     = h + (size_t)N * 64;
    float* bArr     = aArr + N;
    int*   C        = (int*)(bArr + N);
    int*   S        = C + (size_t)G * B;
    int*   binStart = S + B;
    int*   offsets  = binStart + (B + 1);
    int*   stRaw    = offsets + (N + 1);
    stRaw = (int*)(((uintptr_t)stRaw + 7) & ~(uintptr_t)7);
    int2*  staging  = (int2*)stRaw;

    // pass1 blocks FIRST so they dispatch early and overlap node transform.
    fused_nt_count_kernel<<<G + NTBLK, 256, 0, stream>>>(
        x, W1, Wp, ei, h, aArr, bArr, C, N, E, G, B);

    colscan_kernel<<<B, 256, 0, stream>>>(C, S, G, B);

    binscan_kernel<<<1, 256, 0, stream>>>(S, binStart, offsets, B, N, E);

    pass2_kernel<<<G, 256, 0, stream>>>(ei, aArr, bArr, bp, C, binStart,
                                        staging, E, G, B);

    localsort_kernel<<<B, 256, 0, stream>>>(binStart, staging, offsets, N);

    denom_hh_kernel<<<(N * 64 + 255) / 256, 256, 0, stream>>>(offsets, staging, h, N);

    aggregate_kernel<<<(N * 64 + 255) / 256, 256, 0, stream>>>(
        offsets, staging, reinterpret_cast<const unsigned*>(h), bias, out, N);
}

// Round 12
// 132.913 us; speedup vs baseline: 5.0516x; 1.2283x over previous
//
#include <hip/hip_runtime.h>

// GAT forward. Atomic-free multisplit sort + wave-per-node consumers.
//   fused:   node_transform (MFMA bf16: h=x@W1 fp32-accum, a=h·Wp[:64],
//            b=h·Wp[64:]) || pass1 per-block LDS histogram of dst>>7
//   colscan/binscan: exclusive scans -> binStart, offsets[N]=E
//   pass2:   re-read edges, num=exp(lrelu(a[dst]+b[src]+bp)), write
//            {dl<<17|src, num} to exact slot binStart[bin]+C[g][bin]+ldsCur
//   localsort: per bin LDS counting sort to exact dst order; emits offsets
//   denom_hh: wave per node: denom = seg-sum of num; hh = h/denom bf16 packed
//            into first half of fp32 h row (in place)
//   aggregate: wave per node, 2 edges per dword gather of hh, coalesced store
// (alpha denominator gathered at SRC per the reference's quirk.)
// NT-MFMA: wave = 16 nodes x 64 ch; A-frag = 8 contiguous fp32 of x row ->
// bf16; B-frag = pre-swizzled W1-bf16 in LDS, one ds_read_b128. Same slot->k
// map for A and B (k dummy index => any consistent bijection is correct).
// C/D: col=lane&15, row=(lane>>4)*4+reg (m89-verified).

#define MAXB 1024          // max dst bins (N/128); 782 for N=100000
#define EPB 4096           // edges per pass1/pass2 block
#define BIN_CAP 2560       // max edges per 128-node bin (mean 1600, sigma 40)

typedef __attribute__((ext_vector_type(8))) short short8v;
typedef __attribute__((ext_vector_type(4))) float floatx4;

static __device__ __forceinline__ float bf2f(unsigned short u) {
    unsigned v = (unsigned)u << 16;
    return __builtin_bit_cast(float, v);
}
static __device__ __forceinline__ unsigned short f2bf(float f) {
    unsigned u = __builtin_bit_cast(unsigned, f);
    u = (u + 0x7FFFu + ((u >> 16) & 1u)) >> 16;   // round-to-nearest-even
    return (unsigned short)u;
}

// ---------------- fused: pass1 histogram (blocks [0,G)) + NT-MFMA ----------
__global__ __launch_bounds__(256) void fused_nt_count_kernel(
    const float* __restrict__ x, const float* __restrict__ W1,
    const float* __restrict__ Wp, const int* __restrict__ ei,
    float* __restrict__ h, float* __restrict__ aArr, float* __restrict__ bArr,
    int* __restrict__ C, int N, int E, int G, int B)
{
    __shared__ __align__(16) unsigned short w1b[4][4][4][16][8]; // [kb][ot][hi][col][j] 16KB
    __shared__ int cnt[MAXB];                                    // pass1: 4 KB
    const int tid = threadIdx.x;

    if (blockIdx.x < G) {
        const int g = blockIdx.x;
        for (int i = tid; i < B; i += 256) cnt[i] = 0;
        __syncthreads();
        const int base = g * EPB;
        #pragma unroll
        for (int k = 0; k < EPB / 256; ++k) {
            int e = base + k * 256 + tid;
            if (e < E) atomicAdd(&cnt[ei[E + e] >> 7], 1);
        }
        __syncthreads();
        for (int i = tid; i < B; i += 256) C[(size_t)g * B + i] = cnt[i];
        return;
    }

    // ---- stage W1 as bf16, swizzled so each B-fragment is contiguous ----
    for (int i = tid; i < 128 * 64; i += 256) {
        int k = i >> 6, o = i & 63;
        w1b[k >> 5][o >> 4][(k >> 3) & 3][o & 15][k & 7] = f2bf(W1[i]);
    }

    const int w = tid >> 6, lane = tid & 63;
    const int hi = lane >> 4, col = lane & 15;
    float wpa4[4], wpb4[4];
    #pragma unroll
    for (int ot = 0; ot < 4; ++ot) {
        wpa4[ot] = Wp[ot * 16 + col];
        wpb4[ot] = Wp[64 + ot * 16 + col];
    }
    __syncthreads();

    const int n0 = (blockIdx.x - G) * 64 + w * 16;
    int arow = n0 + col; if (arow >= N) arow = N - 1;
    const float* xrow = x + (size_t)arow * 128 + hi * 8;

    floatx4 acc[4] = {{0.f,0.f,0.f,0.f},{0.f,0.f,0.f,0.f},
                      {0.f,0.f,0.f,0.f},{0.f,0.f,0.f,0.f}};
    #pragma unroll
    for (int kb = 0; kb < 4; ++kb) {
        float4 x0 = *reinterpret_cast<const float4*>(xrow + kb * 32);
        float4 x1 = *reinterpret_cast<const float4*>(xrow + kb * 32 + 4);
        short8v af;
        af[0] = (short)f2bf(x0.x); af[1] = (short)f2bf(x0.y);
        af[2] = (short)f2bf(x0.z); af[3] = (short)f2bf(x0.w);
        af[4] = (short)f2bf(x1.x); af[5] = (short)f2bf(x1.y);
        af[6] = (short)f2bf(x1.z); af[7] = (short)f2bf(x1.w);
        #pragma unroll
        for (int ot = 0; ot < 4; ++ot) {
            short8v bf = *reinterpret_cast<const short8v*>(&w1b[kb][ot][hi][col][0]);
            acc[ot] = __builtin_amdgcn_mfma_f32_16x16x32_bf16(af, bf, acc[ot], 0, 0, 0);
        }
    }

    // ---- epilogue: h store (fp32) ----
    #pragma unroll
    for (int ot = 0; ot < 4; ++ot) {
        #pragma unroll
        for (int r = 0; r < 4; ++r) {
            int n = n0 + hi * 4 + r;
            if (n < N) h[(size_t)n * 64 + ot * 16 + col] = acc[ot][r];
        }
    }
    // ---- a/b projections from accumulators ----
    #pragma unroll
    for (int r = 0; r < 4; ++r) {
        float pa = acc[0][r] * wpa4[0] + acc[1][r] * wpa4[1]
                 + acc[2][r] * wpa4[2] + acc[3][r] * wpa4[3];
        float pb = acc[0][r] * wpb4[0] + acc[1][r] * wpb4[1]
                 + acc[2][r] * wpb4[2] + acc[3][r] * wpb4[3];
        #pragma unroll
        for (int m = 1; m <= 8; m <<= 1) {
            pa += __shfl_xor(pa, m);
            pb += __shfl_xor(pb, m);
        }
        int n = n0 + hi * 4 + r;
        if (col == r && n < N) { aArr[n] = pa; bArr[n] = pb; }
    }
}

// ---- colscan: one block per bin; exclusive prefix over blocks, in place ----
__global__ __launch_bounds__(256) void colscan_kernel(
    int* __restrict__ C, int* __restrict__ S, int G, int B)
{
    __shared__ int s[256];
    const int b = blockIdx.x, t = threadIdx.x;
    int g0 = 2 * t, g1 = 2 * t + 1;
    int c0 = (g0 < G) ? C[(size_t)g0 * B + b] : 0;
    int c1 = (g1 < G) ? C[(size_t)g1 * B + b] : 0;
    int v = c0 + c1;
    s[t] = v;
    __syncthreads();
    for (int off = 1; off < 256; off <<= 1) {
        int u = (t >= off) ? s[t - off] : 0;
        __syncthreads();
        s[t] += u;
        __syncthreads();
    }
    int ex = s[t] - v;
    if (g0 < G) C[(size_t)g0 * B + b] = ex;
    if (g1 < G) C[(size_t)g1 * B + b] = ex + c0;
    if (t == 255) S[b] = s[255];
}

// ---- binscan: exclusive scan of S[B] -> binStart[B+1]; offsets[N]=E --------
__global__ __launch_bounds__(256) void binscan_kernel(
    const int* __restrict__ S, int* __restrict__ binStart,
    int* __restrict__ offsets, int B, int N, int E)
{
    __shared__ int ts[256];
    const int t = threadIdx.x;
    const int chunk = (B + 255) >> 8;
    const int base = t * chunk, lim = min(B, base + chunk);
    int s = 0;
    for (int i = base; i < lim; ++i) s += S[i];
    ts[t] = s;
    __syncthreads();
    for (int off = 1; off < 256; off <<= 1) {
        int u = (t >= off) ? ts[t - off] : 0;
        __syncthreads();
        ts[t] += u;
        __syncthreads();
    }
    int run = ts[t] - s;
    for (int i = base; i < lim; ++i) { binStart[i] = run; run += S[i]; }
    if (t == 0) { binStart[B] = E; offsets[N] = E; }
}

// ---- pass2: deterministic multisplit scatter (LDS cursors, no glb atomics) --
__global__ __launch_bounds__(256) void pass2_kernel(
    const int* __restrict__ ei, const float* __restrict__ aArr,
    const float* __restrict__ bArr, const float* __restrict__ bp,
    const int* __restrict__ C, const int* __restrict__ binStart,
    int2* __restrict__ staging, int E, int G, int B)
{
    __shared__ int cur[MAXB];
    const int g = blockIdx.x, t = threadIdx.x;
    for (int i = t; i < B; i += 256)
        cur[i] = binStart[i] + C[(size_t)g * B + i];
    __syncthreads();
    const float bp0 = bp[0];
    const int base = g * EPB;
    #pragma unroll
    for (int k = 0; k < EPB / 256; ++k) {
        int e = base + k * 256 + t;
        if (e >= E) break;
        int src = ei[e];
        int dst = ei[E + e];
        float s = aArr[dst] + bArr[src] + bp0;
        s = (s >= 0.f) ? s : 0.2f * s;
        float num = __expf(s);
        int bin = dst >> 7;
        int pos = atomicAdd(&cur[bin], 1);   // LDS atomic
        staging[pos] = make_int2(((dst & 127) << 17) | src, __float_as_int(num));
    }
}

// ---- localsort: per bin, exact dst order in place + CSR offsets ------------
__global__ __launch_bounds__(256) void localsort_kernel(
    const int* __restrict__ binStart, int2* __restrict__ staging,
    int* __restrict__ offsets, int N)
{
    __shared__ int2 sEnt[BIN_CAP];       // 20 KB
    __shared__ int sCnt[256], sScan[256], sCur[128];
    const int b = blockIdx.x, t = threadIdx.x;
    const int sBeg = binStart[b];
    const int count = min(binStart[b + 1] - sBeg, BIN_CAP);

    sCnt[t] = 0;
    if (t < 128) sCur[t] = 0;
    __syncthreads();
    for (int i = t; i < count; i += 256) {
        int2 e = staging[sBeg + i];
        sEnt[i] = e;
        atomicAdd(&sCnt[e.x >> 17], 1);
    }
    __syncthreads();
    int v = sCnt[t];
    sScan[t] = v;
    __syncthreads();
    for (int off = 1; off < 256; off <<= 1) {
        int u = (t >= off) ? sScan[t - off] : 0;
        __syncthreads();
        sScan[t] += u;
        __syncthreads();
    }
    int ex = sScan[t] - v;
    __syncthreads();
    sScan[t] = ex;                       // exclusive scan in place
    const int n0 = b << 7;
    const int Cl = min(128, N - n0);
    if (t < Cl) offsets[n0 + t] = sBeg + ex;
    __syncthreads();
    for (int i = t; i < count; i += 256) {
        int2 e = sEnt[i];
        int dl = e.x >> 17;
        int pos = sBeg + sScan[dl] + atomicAdd(&sCur[dl], 1);
        staging[pos] = make_int2(e.x & 0x1FFFF, e.y);   // {src, num}
    }
}

// ---------------- denom + hh: wave per node ----------------
__global__ __launch_bounds__(256) void denom_hh_kernel(
    const int* __restrict__ offsets, const int2* __restrict__ sortedPair,
    float* __restrict__ h, int N)
{
    int gw = (blockIdx.x * blockDim.x + threadIdx.x) >> 6;
    int lane = threadIdx.x & 63;
    if (gw >= N) return;
    int beg = offsets[gw], end = offsets[gw + 1];
    float s = 0.f;
    for (int e = beg + lane; e < end; e += 64) s += __int_as_float(sortedPair[e].y);
    #pragma unroll
    for (int off = 32; off; off >>= 1) s += __shfl_down(s, off);
    s = __shfl(s, 0);
    float inv = 1.f / (s + 1e-16f);
    float hv = h[(size_t)gw * 64 + lane];
    asm volatile("" ::: "memory");   // order read-before-aliased-write
    unsigned short* row = reinterpret_cast<unsigned short*>(h) + (size_t)gw * 128;
    row[lane] = f2bf(hv * inv);
}

// ---------------- aggregate: wave per dst node, 2 edges per gather ----------
// hh row = 64 bf16 in the first 32 dwords of a 64-dword fp32 row (base s*64).
__global__ __launch_bounds__(256) void aggregate_kernel(
    const int* __restrict__ offsets, const int2* __restrict__ sortedPair,
    const unsigned* __restrict__ hhW, const float* __restrict__ bias,
    float* __restrict__ out, int N)
{
    int gw = (blockIdx.x * blockDim.x + threadIdx.x) >> 6;
    int lane = threadIdx.x & 63;
    if (gw >= N) return;
    int beg = offsets[gw], end = offsets[gw + 1];
    const int half = lane >> 5;
    const int cp = lane & 31;
    float accx = 0.f, accy = 0.f;
    for (int e0 = beg; e0 < end; e0 += 64) {
        int idx = e0 + lane;
        int2 p = (idx < end) ? sortedPair[idx] : make_int2(0, 0);
        int cnt = min(64, end - e0);
        int j = 0;
        for (; j + 8 <= cnt; j += 8) {
            #pragma unroll
            for (int u = 0; u < 4; ++u) {
                int jj = j + 2 * u + half;
                int s = __shfl(p.x, jj);
                float wv = __shfl(__int_as_float(p.y), jj);
                unsigned g = hhW[(size_t)s * 64 + cp];
                accx = fmaf(bf2f((unsigned short)(g & 0xFFFFu)), wv, accx);
                accy = fmaf(bf2f((unsigned short)(g >> 16)), wv, accy);
            }
        }
        for (; j < cnt; j += 2) {
            int jj = j + half;
            bool v = jj < cnt;
            int s = __shfl(p.x, v ? jj : j);
            float wv = v ? __shfl(__int_as_float(p.y), jj) : 0.f;
            unsigned g = hhW[(size_t)s * 64 + cp];
            accx = fmaf(bf2f((unsigned short)(g & 0xFFFFu)), wv, accx);
            accy = fmaf(bf2f((unsigned short)(g >> 16)), wv, accy);
        }
    }
    accx += __shfl_xor(accx, 32);
    accy += __shfl_xor(accy, 32);
    if (lane < 32) {
        float2 b = reinterpret_cast<const float2*>(bias)[cp];
        float2 o; o.x = accx + b.x; o.y = accy + b.y;
        reinterpret_cast<float2*>(out)[(size_t)gw * 32 + cp] = o;
    }
}

extern "C" void kernel_launch(void* const* d_in, const int* in_sizes, int n_in,
                              void* d_out, int out_size, void* d_ws, size_t ws_size,
                              hipStream_t stream) {
    const float* x    = (const float*)d_in[0];
    const int*   ei   = (const int*)d_in[1];
    // d_in[2] = rank_mapping (unused)
    const float* W1   = (const float*)d_in[3];
    const float* Wp   = (const float*)d_in[4];
    const float* bp   = (const float*)d_in[5];
    const float* bias = (const float*)d_in[6];
    float* out = (float*)d_out;

    const int N = in_sizes[0] / 128;
    const int E = in_sizes[1] / 2;
    const int B = (N + 127) >> 7;        // dst bins of 128 nodes (782)
    const int G = (E + EPB - 1) / EPB;   // pass1/pass2 blocks (306)
    const int NTB = (N + 63) / 64;       // NT blocks, 64 nodes each (1563)

    // workspace (4B units):
    // h[N*64] | a[N] | b[N] | C[G*B] | S[B] | binStart[B+1] | offsets[N+1] |
    // staging[E] int2
    float* h        = (float*)d_ws;
    float* aArr     = h + (size_t)N * 64;
    float* bArr     = aArr + N;
    int*   C        = (int*)(bArr + N);
    int*   S        = C + (size_t)G * B;
    int*   binStart = S + B;
    int*   offsets  = binStart + (B + 1);
    int*   stRaw    = offsets + (N + 1);
    stRaw = (int*)(((uintptr_t)stRaw + 7) & ~(uintptr_t)7);
    int2*  staging  = (int2*)stRaw;

    // pass1 blocks FIRST so they dispatch early and overlap node transform.
    fused_nt_count_kernel<<<G + NTB, 256, 0, stream>>>(
        x, W1, Wp, ei, h, aArr, bArr, C, N, E, G, B);

    colscan_kernel<<<B, 256, 0, stream>>>(C, S, G, B);

    binscan_kernel<<<1, 256, 0, stream>>>(S, binStart, offsets, B, N, E);

    pass2_kernel<<<G, 256, 0, stream>>>(ei, aArr, bArr, bp, C, binStart,
                                        staging, E, G, B);

    localsort_kernel<<<B, 256, 0, stream>>>(binStart, staging, offsets, N);

    denom_hh_kernel<<<(N * 64 + 255) / 256, 256, 0, stream>>>(offsets, staging, h, N);

    aggregate_kernel<<<(N * 64 + 255) / 256, 256, 0, stream>>>(
        offsets, staging, reinterpret_cast<const unsigned*>(h), bias, out, N);
}

// Round 13
// 128.312 us; speedup vs baseline: 5.2327x; 1.0359x over previous
//
#include <hip/hip_runtime.h>

// GAT forward. Atomic-free multisplit sort + wave-per-node consumers.
//   fused:   node_transform (MFMA bf16: h=x@W1 fp32-accum, a=h·Wp[:64],
//            b=h·Wp[64:]) || pass1 per-block LDS histogram of dst>>7
//   colscan/binscan: exclusive scans -> binStart, offsets[N]=E
//   pass2:   re-read edges, num=exp(lrelu(a[dst]+b[src]+bp)), write
//            {dl<<17|src, num} to exact slot binStart[bin]+C[g][bin]+ldsCur
//   localsort: per bin LDS counting sort to exact dst order; emits offsets;
//            FUSED: denom[128] via LDS atomics + hh = h/denom bf16 pack
//   aggregate: wave per node, 4 edges per dwordx2 gather of hh, float4 store
// (alpha denominator gathered at SRC per the reference's quirk.)

#define MAXB 1024          // max dst bins (N/128); 782 for N=100000
#define EPB 4096           // edges per pass1/pass2 block
#define BIN_CAP 2560       // max edges per 128-node bin (mean 1600, sigma 40)

typedef __attribute__((ext_vector_type(8))) short short8v;
typedef __attribute__((ext_vector_type(4))) float floatx4;

static __device__ __forceinline__ float bf2f(unsigned short u) {
    unsigned v = (unsigned)u << 16;
    return __builtin_bit_cast(float, v);
}
static __device__ __forceinline__ unsigned short f2bf(float f) {
    unsigned u = __builtin_bit_cast(unsigned, f);
    u = (u + 0x7FFFu + ((u >> 16) & 1u)) >> 16;   // round-to-nearest-even
    return (unsigned short)u;
}

// ---------------- fused: pass1 histogram (blocks [0,G)) + NT-MFMA ----------
__global__ __launch_bounds__(256) void fused_nt_count_kernel(
    const float* __restrict__ x, const float* __restrict__ W1,
    const float* __restrict__ Wp, const int* __restrict__ ei,
    float* __restrict__ h, float* __restrict__ aArr, float* __restrict__ bArr,
    int* __restrict__ C, int N, int E, int G, int B)
{
    __shared__ __align__(16) unsigned short w1b[4][4][4][16][8]; // [kb][ot][hi][col][j] 16KB
    __shared__ int cnt[MAXB];                                    // pass1: 4 KB
    const int tid = threadIdx.x;

    if (blockIdx.x < G) {
        const int g = blockIdx.x;
        for (int i = tid; i < B; i += 256) cnt[i] = 0;
        __syncthreads();
        const int base = g * EPB;
        #pragma unroll
        for (int k = 0; k < EPB / 256; ++k) {
            int e = base + k * 256 + tid;
            if (e < E) atomicAdd(&cnt[ei[E + e] >> 7], 1);
        }
        __syncthreads();
        for (int i = tid; i < B; i += 256) C[(size_t)g * B + i] = cnt[i];
        return;
    }

    // ---- stage W1 as bf16, swizzled so each B-fragment is contiguous ----
    for (int i = tid; i < 128 * 64; i += 256) {
        int k = i >> 6, o = i & 63;
        w1b[k >> 5][o >> 4][(k >> 3) & 3][o & 15][k & 7] = f2bf(W1[i]);
    }

    const int w = tid >> 6, lane = tid & 63;
    const int hi = lane >> 4, col = lane & 15;
    float wpa4[4], wpb4[4];
    #pragma unroll
    for (int ot = 0; ot < 4; ++ot) {
        wpa4[ot] = Wp[ot * 16 + col];
        wpb4[ot] = Wp[64 + ot * 16 + col];
    }
    __syncthreads();

    const int n0 = (blockIdx.x - G) * 64 + w * 16;
    int arow = n0 + col; if (arow >= N) arow = N - 1;
    const float* xrow = x + (size_t)arow * 128 + hi * 8;

    floatx4 acc[4] = {{0.f,0.f,0.f,0.f},{0.f,0.f,0.f,0.f},
                      {0.f,0.f,0.f,0.f},{0.f,0.f,0.f,0.f}};
    #pragma unroll
    for (int kb = 0; kb < 4; ++kb) {
        float4 x0 = *reinterpret_cast<const float4*>(xrow + kb * 32);
        float4 x1 = *reinterpret_cast<const float4*>(xrow + kb * 32 + 4);
        short8v af;
        af[0] = (short)f2bf(x0.x); af[1] = (short)f2bf(x0.y);
        af[2] = (short)f2bf(x0.z); af[3] = (short)f2bf(x0.w);
        af[4] = (short)f2bf(x1.x); af[5] = (short)f2bf(x1.y);
        af[6] = (short)f2bf(x1.z); af[7] = (short)f2bf(x1.w);
        #pragma unroll
        for (int ot = 0; ot < 4; ++ot) {
            short8v bf = *reinterpret_cast<const short8v*>(&w1b[kb][ot][hi][col][0]);
            acc[ot] = __builtin_amdgcn_mfma_f32_16x16x32_bf16(af, bf, acc[ot], 0, 0, 0);
        }
    }

    // ---- epilogue: h store (fp32) ----
    #pragma unroll
    for (int ot = 0; ot < 4; ++ot) {
        #pragma unroll
        for (int r = 0; r < 4; ++r) {
            int n = n0 + hi * 4 + r;
            if (n < N) h[(size_t)n * 64 + ot * 16 + col] = acc[ot][r];
        }
    }
    // ---- a/b projections from accumulators ----
    #pragma unroll
    for (int r = 0; r < 4; ++r) {
        float pa = acc[0][r] * wpa4[0] + acc[1][r] * wpa4[1]
                 + acc[2][r] * wpa4[2] + acc[3][r] * wpa4[3];
        float pb = acc[0][r] * wpb4[0] + acc[1][r] * wpb4[1]
                 + acc[2][r] * wpb4[2] + acc[3][r] * wpb4[3];
        #pragma unroll
        for (int m = 1; m <= 8; m <<= 1) {
            pa += __shfl_xor(pa, m);
            pb += __shfl_xor(pb, m);
        }
        int n = n0 + hi * 4 + r;
        if (col == r && n < N) { aArr[n] = pa; bArr[n] = pb; }
    }
}

// ---- colscan: one block per bin; exclusive prefix over blocks, in place ----
__global__ __launch_bounds__(256) void colscan_kernel(
    int* __restrict__ C, int* __restrict__ S, int G, int B)
{
    __shared__ int s[256];
    const int b = blockIdx.x, t = threadIdx.x;
    int g0 = 2 * t, g1 = 2 * t + 1;
    int c0 = (g0 < G) ? C[(size_t)g0 * B + b] : 0;
    int c1 = (g1 < G) ? C[(size_t)g1 * B + b] : 0;
    int v = c0 + c1;
    s[t] = v;
    __syncthreads();
    for (int off = 1; off < 256; off <<= 1) {
        int u = (t >= off) ? s[t - off] : 0;
        __syncthreads();
        s[t] += u;
        __syncthreads();
    }
    int ex = s[t] - v;
    if (g0 < G) C[(size_t)g0 * B + b] = ex;
    if (g1 < G) C[(size_t)g1 * B + b] = ex + c0;
    if (t == 255) S[b] = s[255];
}

// ---- binscan: exclusive scan of S[B] -> binStart[B+1]; offsets[N]=E --------
__global__ __launch_bounds__(256) void binscan_kernel(
    const int* __restrict__ S, int* __restrict__ binStart,
    int* __restrict__ offsets, int B, int N, int E)
{
    __shared__ int ts[256];
    const int t = threadIdx.x;
    const int chunk = (B + 255) >> 8;
    const int base = t * chunk, lim = min(B, base + chunk);
    int s = 0;
    for (int i = base; i < lim; ++i) s += S[i];
    ts[t] = s;
    __syncthreads();
    for (int off = 1; off < 256; off <<= 1) {
        int u = (t >= off) ? ts[t - off] : 0;
        __syncthreads();
        ts[t] += u;
        __syncthreads();
    }
    int run = ts[t] - s;
    for (int i = base; i < lim; ++i) { binStart[i] = run; run += S[i]; }
    if (t == 0) { binStart[B] = E; offsets[N] = E; }
}

// ---- pass2: deterministic multisplit scatter (LDS cursors, no glb atomics) --
__global__ __launch_bounds__(256) void pass2_kernel(
    const int* __restrict__ ei, const float* __restrict__ aArr,
    const float* __restrict__ bArr, const float* __restrict__ bp,
    const int* __restrict__ C, const int* __restrict__ binStart,
    int2* __restrict__ staging, int E, int G, int B)
{
    __shared__ int cur[MAXB];
    const int g = blockIdx.x, t = threadIdx.x;
    for (int i = t; i < B; i += 256)
        cur[i] = binStart[i] + C[(size_t)g * B + i];
    __syncthreads();
    const float bp0 = bp[0];
    const int base = g * EPB;
    #pragma unroll
    for (int k = 0; k < EPB / 256; ++k) {
        int e = base + k * 256 + t;
        if (e >= E) break;
        int src = ei[e];
        int dst = ei[E + e];
        float s = aArr[dst] + bArr[src] + bp0;
        s = (s >= 0.f) ? s : 0.2f * s;
        float num = __expf(s);
        int bin = dst >> 7;
        int pos = atomicAdd(&cur[bin], 1);   // LDS atomic
        staging[pos] = make_int2(((dst & 127) << 17) | src, __float_as_int(num));
    }
}

// ---- localsort: per bin, exact dst order in place + CSR offsets + denom/hh -
__global__ __launch_bounds__(256) void localsort_kernel(
    const int* __restrict__ binStart, int2* __restrict__ staging,
    int* __restrict__ offsets, float* __restrict__ h, int N)
{
    __shared__ int2 sEnt[BIN_CAP];       // 20 KB
    __shared__ int sCnt[256], sScan[256], sCur[128];
    __shared__ float dsum[128];
    const int b = blockIdx.x, t = threadIdx.x;
    const int sBeg = binStart[b];
    const int count = min(binStart[b + 1] - sBeg, BIN_CAP);

    sCnt[t] = 0;
    if (t < 128) { sCur[t] = 0; dsum[t] = 0.f; }
    __syncthreads();
    for (int i = t; i < count; i += 256) {
        int2 e = staging[sBeg + i];
        sEnt[i] = e;
        int dl = e.x >> 17;
        atomicAdd(&sCnt[dl], 1);
        atomicAdd(&dsum[dl], __int_as_float(e.y));
    }
    __syncthreads();
    int v = sCnt[t];
    sScan[t] = v;
    __syncthreads();
    for (int off = 1; off < 256; off <<= 1) {
        int u = (t >= off) ? sScan[t - off] : 0;
        __syncthreads();
        sScan[t] += u;
        __syncthreads();
    }
    int ex = sScan[t] - v;
    __syncthreads();
    sScan[t] = ex;                       // exclusive scan in place
    const int n0 = b << 7;
    const int Cl = min(128, N - n0);
    if (t < Cl) offsets[n0 + t] = sBeg + ex;
    __syncthreads();
    for (int i = t; i < count; i += 256) {
        int2 e = sEnt[i];
        int dl = e.x >> 17;
        int pos = sBeg + sScan[dl] + atomicAdd(&sCur[dl], 1);
        staging[pos] = make_int2(e.x & 0x1FFFF, e.y);   // {src, num}
    }

    // ---- fused hh: wave per row; read fp32 row then pack bf16 in place.
    // Same-wave read-before-write (all 64 lane-reads complete before stores).
    const int wv_ = t >> 6, ln = t & 63;
    for (int dl = wv_; dl < Cl; dl += 4) {
        int n = n0 + dl;
        float inv = 1.f / (dsum[dl] + 1e-16f);
        float hv = h[(size_t)n * 64 + ln];
        asm volatile("" ::: "memory");   // keep read before aliased write
        reinterpret_cast<unsigned short*>(h)[(size_t)n * 128 + ln] = f2bf(hv * inv);
    }
}

// ---------------- aggregate: wave per dst node, 4 edges per dwordx2 gather --
// hh row = 64 bf16 = 32 dwords = 16 uint2, in the first half of a 64-dword
// fp32 row: uint2 row stride is 32 (NOT 16 — round-5 stride lesson).
// quarter = lane>>4 picks edge j..j+3; cg = lane&15 picks a bf16x4 ch group.
// Invalid preload lanes hold (0,0) => num 0; max shfl index 63 by construction.
__global__ __launch_bounds__(256) void aggregate_kernel(
    const int* __restrict__ offsets, const int2* __restrict__ sortedPair,
    const uint2* __restrict__ hhQ, const float* __restrict__ bias,
    float* __restrict__ out, int N)
{
    int gw = (blockIdx.x * blockDim.x + threadIdx.x) >> 6;
    int lane = threadIdx.x & 63;
    if (gw >= N) return;
    int beg = offsets[gw], end = offsets[gw + 1];
    const int quarter = lane >> 4;
    const int cg = lane & 15;
    float a0 = 0.f, a1 = 0.f, a2 = 0.f, a3 = 0.f;
    for (int e0 = beg; e0 < end; e0 += 64) {
        int idx = e0 + lane;
        int2 p = (idx < end) ? sortedPair[idx] : make_int2(0, 0);
        int cnt = min(64, end - e0);
        int j = 0;
        for (; j + 16 <= cnt; j += 16) {
            #pragma unroll
            for (int u = 0; u < 4; ++u) {
                int jj = j + 4 * u + quarter;
                int s = __shfl(p.x, jj);
                float wv = __shfl(__int_as_float(p.y), jj);
                uint2 g = hhQ[(size_t)s * 32 + cg];
                a0 = fmaf(bf2f((unsigned short)(g.x & 0xFFFFu)), wv, a0);
                a1 = fmaf(bf2f((unsigned short)(g.x >> 16)), wv, a1);
                a2 = fmaf(bf2f((unsigned short)(g.y & 0xFFFFu)), wv, a2);
                a3 = fmaf(bf2f((unsigned short)(g.y >> 16)), wv, a3);
            }
        }
        for (; j < cnt; j += 4) {
            int jj = j + quarter;           // <= 63 always (j<=60, quarter<=3)
            int s = __shfl(p.x, jj);
            float wv = __shfl(__int_as_float(p.y), jj);
            uint2 g = hhQ[(size_t)s * 32 + cg];
            a0 = fmaf(bf2f((unsigned short)(g.x & 0xFFFFu)), wv, a0);
            a1 = fmaf(bf2f((unsigned short)(g.x >> 16)), wv, a1);
            a2 = fmaf(bf2f((unsigned short)(g.y & 0xFFFFu)), wv, a2);
            a3 = fmaf(bf2f((unsigned short)(g.y >> 16)), wv, a3);
        }
    }
    a0 += __shfl_xor(a0, 16); a0 += __shfl_xor(a0, 32);
    a1 += __shfl_xor(a1, 16); a1 += __shfl_xor(a1, 32);
    a2 += __shfl_xor(a2, 16); a2 += __shfl_xor(a2, 32);
    a3 += __shfl_xor(a3, 16); a3 += __shfl_xor(a3, 32);
    if (lane < 16) {
        float4 bq = reinterpret_cast<const float4*>(bias)[cg];
        float4 o;
        o.x = a0 + bq.x; o.y = a1 + bq.y; o.z = a2 + bq.z; o.w = a3 + bq.w;
        reinterpret_cast<float4*>(out)[(size_t)gw * 16 + cg] = o;
    }
}

extern "C" void kernel_launch(void* const* d_in, const int* in_sizes, int n_in,
                              void* d_out, int out_size, void* d_ws, size_t ws_size,
                              hipStream_t stream) {
    const float* x    = (const float*)d_in[0];
    const int*   ei   = (const int*)d_in[1];
    // d_in[2] = rank_mapping (unused)
    const float* W1   = (const float*)d_in[3];
    const float* Wp   = (const float*)d_in[4];
    const float* bp   = (const float*)d_in[5];
    const float* bias = (const float*)d_in[6];
    float* out = (float*)d_out;

    const int N = in_sizes[0] / 128;
    const int E = in_sizes[1] / 2;
    const int B = (N + 127) >> 7;        // dst bins of 128 nodes (782)
    const int G = (E + EPB - 1) / EPB;   // pass1/pass2 blocks (306)
    const int NTB = (N + 63) / 64;       // NT blocks, 64 nodes each (1563)

    // workspace (4B units):
    // h[N*64] | a[N] | b[N] | C[G*B] | S[B] | binStart[B+1] | offsets[N+1] |
    // staging[E] int2
    float* h        = (float*)d_ws;
    float* aArr     = h + (size_t)N * 64;
    float* bArr     = aArr + N;
    int*   C        = (int*)(bArr + N);
    int*   S        = C + (size_t)G * B;
    int*   binStart = S + B;
    int*   offsets  = binStart + (B + 1);
    int*   stRaw    = offsets + (N + 1);
    stRaw = (int*)(((uintptr_t)stRaw + 7) & ~(uintptr_t)7);
    int2*  staging  = (int2*)stRaw;

    // pass1 blocks FIRST so they dispatch early and overlap node transform.
    fused_nt_count_kernel<<<G + NTB, 256, 0, stream>>>(
        x, W1, Wp, ei, h, aArr, bArr, C, N, E, G, B);

    colscan_kernel<<<B, 256, 0, stream>>>(C, S, G, B);

    binscan_kernel<<<1, 256, 0, stream>>>(S, binStart, offsets, B, N, E);

    pass2_kernel<<<G, 256, 0, stream>>>(ei, aArr, bArr, bp, C, binStart,
                                        staging, E, G, B);

    localsort_kernel<<<B, 256, 0, stream>>>(binStart, staging, offsets, h, N);

    aggregate_kernel<<<(N * 64 + 255) / 256, 256, 0, stream>>>(
        offsets, staging, reinterpret_cast<const uint2*>(h), bias, out, N);
}

// Round 14
// 127.102 us; speedup vs baseline: 5.2825x; 1.0095x over previous
//
#include <hip/hip_runtime.h>

// GAT forward. Atomic-free multisplit sort + wave-per-node consumers.
//   fused:   node_transform (MFMA bf16: h=x@W1 fp32-accum, a=h·Wp[:64],
//            b=h·Wp[64:]) || pass1 per-block LDS histogram of dst>>7
//   colscan/binscan: exclusive scans -> binStart, offsets[N]=E
//   pass2:   re-read edges, num=exp(lrelu(a[dst]+b[src]+bp)), write
//            {dl<<17|src, num} to exact slot binStart[bin]+C[g][bin]+ldsCur
//            (1024 threads/block: 16 waves share the LDS cursors — slot SET
//            per block is deterministic; within-bin order is not, but both
//            consumers are order-independent sums)
//   localsort: per bin LDS counting sort to exact dst order; emits offsets;
//            FUSED: denom[128] via LDS atomics + hh = h/denom bf16 pack
//   aggregate: wave per node, 4 edges per dwordx2 gather of hh, float4 store
// (alpha denominator gathered at SRC per the reference's quirk.)

#define MAXB 1024          // max dst bins (N/128); 782 for N=100000
#define EPB 4096           // edges per pass1/pass2 block
#define BIN_CAP 2560       // max edges per 128-node bin (mean 1600, sigma 40)

typedef __attribute__((ext_vector_type(8))) short short8v;
typedef __attribute__((ext_vector_type(4))) float floatx4;

static __device__ __forceinline__ float bf2f(unsigned short u) {
    unsigned v = (unsigned)u << 16;
    return __builtin_bit_cast(float, v);
}
static __device__ __forceinline__ unsigned short f2bf(float f) {
    unsigned u = __builtin_bit_cast(unsigned, f);
    u = (u + 0x7FFFu + ((u >> 16) & 1u)) >> 16;   // round-to-nearest-even
    return (unsigned short)u;
}

// ---------------- fused: pass1 histogram (blocks [0,G)) + NT-MFMA ----------
__global__ __launch_bounds__(256) void fused_nt_count_kernel(
    const float* __restrict__ x, const float* __restrict__ W1,
    const float* __restrict__ Wp, const int* __restrict__ ei,
    float* __restrict__ h, float* __restrict__ aArr, float* __restrict__ bArr,
    int* __restrict__ C, int N, int E, int G, int B)
{
    __shared__ __align__(16) unsigned short w1b[4][4][4][16][8]; // [kb][ot][hi][col][j] 16KB
    __shared__ int cnt[MAXB];                                    // pass1: 4 KB
    const int tid = threadIdx.x;

    if (blockIdx.x < G) {
        const int g = blockIdx.x;
        for (int i = tid; i < B; i += 256) cnt[i] = 0;
        __syncthreads();
        const int base = g * EPB;
        #pragma unroll
        for (int k = 0; k < EPB / 256; ++k) {
            int e = base + k * 256 + tid;
            if (e < E) atomicAdd(&cnt[ei[E + e] >> 7], 1);
        }
        __syncthreads();
        for (int i = tid; i < B; i += 256) C[(size_t)g * B + i] = cnt[i];
        return;
    }

    // ---- stage W1 as bf16, swizzled so each B-fragment is contiguous ----
    for (int i = tid; i < 128 * 64; i += 256) {
        int k = i >> 6, o = i & 63;
        w1b[k >> 5][o >> 4][(k >> 3) & 3][o & 15][k & 7] = f2bf(W1[i]);
    }

    const int w = tid >> 6, lane = tid & 63;
    const int hi = lane >> 4, col = lane & 15;
    float wpa4[4], wpb4[4];
    #pragma unroll
    for (int ot = 0; ot < 4; ++ot) {
        wpa4[ot] = Wp[ot * 16 + col];
        wpb4[ot] = Wp[64 + ot * 16 + col];
    }
    __syncthreads();

    const int n0 = (blockIdx.x - G) * 64 + w * 16;
    int arow = n0 + col; if (arow >= N) arow = N - 1;
    const float* xrow = x + (size_t)arow * 128 + hi * 8;

    floatx4 acc[4] = {{0.f,0.f,0.f,0.f},{0.f,0.f,0.f,0.f},
                      {0.f,0.f,0.f,0.f},{0.f,0.f,0.f,0.f}};
    #pragma unroll
    for (int kb = 0; kb < 4; ++kb) {
        float4 x0 = *reinterpret_cast<const float4*>(xrow + kb * 32);
        float4 x1 = *reinterpret_cast<const float4*>(xrow + kb * 32 + 4);
        short8v af;
        af[0] = (short)f2bf(x0.x); af[1] = (short)f2bf(x0.y);
        af[2] = (short)f2bf(x0.z); af[3] = (short)f2bf(x0.w);
        af[4] = (short)f2bf(x1.x); af[5] = (short)f2bf(x1.y);
        af[6] = (short)f2bf(x1.z); af[7] = (short)f2bf(x1.w);
        #pragma unroll
        for (int ot = 0; ot < 4; ++ot) {
            short8v bf = *reinterpret_cast<const short8v*>(&w1b[kb][ot][hi][col][0]);
            acc[ot] = __builtin_amdgcn_mfma_f32_16x16x32_bf16(af, bf, acc[ot], 0, 0, 0);
        }
    }

    // ---- epilogue: h store (fp32) ----
    #pragma unroll
    for (int ot = 0; ot < 4; ++ot) {
        #pragma unroll
        for (int r = 0; r < 4; ++r) {
            int n = n0 + hi * 4 + r;
            if (n < N) h[(size_t)n * 64 + ot * 16 + col] = acc[ot][r];
        }
    }
    // ---- a/b projections from accumulators ----
    #pragma unroll
    for (int r = 0; r < 4; ++r) {
        float pa = acc[0][r] * wpa4[0] + acc[1][r] * wpa4[1]
                 + acc[2][r] * wpa4[2] + acc[3][r] * wpa4[3];
        float pb = acc[0][r] * wpb4[0] + acc[1][r] * wpb4[1]
                 + acc[2][r] * wpb4[2] + acc[3][r] * wpb4[3];
        #pragma unroll
        for (int m = 1; m <= 8; m <<= 1) {
            pa += __shfl_xor(pa, m);
            pb += __shfl_xor(pb, m);
        }
        int n = n0 + hi * 4 + r;
        if (col == r && n < N) { aArr[n] = pa; bArr[n] = pb; }
    }
}

// ---- colscan: one block per bin; exclusive prefix over blocks, in place ----
__global__ __launch_bounds__(256) void colscan_kernel(
    int* __restrict__ C, int* __restrict__ S, int G, int B)
{
    __shared__ int s[256];
    const int b = blockIdx.x, t = threadIdx.x;
    int g0 = 2 * t, g1 = 2 * t + 1;
    int c0 = (g0 < G) ? C[(size_t)g0 * B + b] : 0;
    int c1 = (g1 < G) ? C[(size_t)g1 * B + b] : 0;
    int v = c0 + c1;
    s[t] = v;
    __syncthreads();
    for (int off = 1; off < 256; off <<= 1) {
        int u = (t >= off) ? s[t - off] : 0;
        __syncthreads();
        s[t] += u;
        __syncthreads();
    }
    int ex = s[t] - v;
    if (g0 < G) C[(size_t)g0 * B + b] = ex;
    if (g1 < G) C[(size_t)g1 * B + b] = ex + c0;
    if (t == 255) S[b] = s[255];
}

// ---- binscan: exclusive scan of S[B] -> binStart[B+1]; offsets[N]=E --------
__global__ __launch_bounds__(256) void binscan_kernel(
    const int* __restrict__ S, int* __restrict__ binStart,
    int* __restrict__ offsets, int B, int N, int E)
{
    __shared__ int ts[256];
    const int t = threadIdx.x;
    const int chunk = (B + 255) >> 8;
    const int base = t * chunk, lim = min(B, base + chunk);
    int s = 0;
    for (int i = base; i < lim; ++i) s += S[i];
    ts[t] = s;
    __syncthreads();
    for (int off = 1; off < 256; off <<= 1) {
        int u = (t >= off) ? ts[t - off] : 0;
        __syncthreads();
        ts[t] += u;
        __syncthreads();
    }
    int run = ts[t] - s;
    for (int i = base; i < lim; ++i) { binStart[i] = run; run += S[i]; }
    if (t == 0) { binStart[B] = E; offsets[N] = E; }
}

// ---- pass2: deterministic multisplit scatter, 1024 thr (16 waves/block) ----
__global__ __launch_bounds__(1024) void pass2_kernel(
    const int* __restrict__ ei, const float* __restrict__ aArr,
    const float* __restrict__ bArr, const float* __restrict__ bp,
    const int* __restrict__ C, const int* __restrict__ binStart,
    int2* __restrict__ staging, int E, int G, int B)
{
    __shared__ int cur[MAXB];
    const int g = blockIdx.x, t = threadIdx.x;
    for (int i = t; i < B; i += 1024)
        cur[i] = binStart[i] + C[(size_t)g * B + i];
    __syncthreads();
    const float bp0 = bp[0];
    const int base = g * EPB;
    #pragma unroll
    for (int k = 0; k < EPB / 1024; ++k) {
        int e = base + k * 1024 + t;
        if (e >= E) break;
        int src = ei[e];
        int dst = ei[E + e];
        float s = aArr[dst] + bArr[src] + bp0;
        s = (s >= 0.f) ? s : 0.2f * s;
        float num = __expf(s);
        int bin = dst >> 7;
        int pos = atomicAdd(&cur[bin], 1);   // LDS atomic
        staging[pos] = make_int2(((dst & 127) << 17) | src, __float_as_int(num));
    }
}

// ---- localsort: per bin, exact dst order in place + CSR offsets + denom/hh -
__global__ __launch_bounds__(256) void localsort_kernel(
    const int* __restrict__ binStart, int2* __restrict__ staging,
    int* __restrict__ offsets, float* __restrict__ h, int N)
{
    __shared__ int2 sEnt[BIN_CAP];       // 20 KB
    __shared__ int sCnt[256], sScan[256], sCur[128];
    __shared__ float dsum[128];
    const int b = blockIdx.x, t = threadIdx.x;
    const int sBeg = binStart[b];
    const int count = min(binStart[b + 1] - sBeg, BIN_CAP);

    sCnt[t] = 0;
    if (t < 128) { sCur[t] = 0; dsum[t] = 0.f; }
    __syncthreads();
    for (int i = t; i < count; i += 256) {
        int2 e = staging[sBeg + i];
        sEnt[i] = e;
        int dl = e.x >> 17;
        atomicAdd(&sCnt[dl], 1);
        atomicAdd(&dsum[dl], __int_as_float(e.y));
    }
    __syncthreads();
    int v = sCnt[t];
    sScan[t] = v;
    __syncthreads();
    for (int off = 1; off < 256; off <<= 1) {
        int u = (t >= off) ? sScan[t - off] : 0;
        __syncthreads();
        sScan[t] += u;
        __syncthreads();
    }
    int ex = sScan[t] - v;
    __syncthreads();
    sScan[t] = ex;                       // exclusive scan in place
    const int n0 = b << 7;
    const int Cl = min(128, N - n0);
    if (t < Cl) offsets[n0 + t] = sBeg + ex;
    __syncthreads();
    for (int i = t; i < count; i += 256) {
        int2 e = sEnt[i];
        int dl = e.x >> 17;
        int pos = sBeg + sScan[dl] + atomicAdd(&sCur[dl], 1);
        staging[pos] = make_int2(e.x & 0x1FFFF, e.y);   // {src, num}
    }

    // ---- fused hh: wave per row; read fp32 row then pack bf16 in place.
    const int wv_ = t >> 6, ln = t & 63;
    for (int dl = wv_; dl < Cl; dl += 4) {
        int n = n0 + dl;
        float inv = 1.f / (dsum[dl] + 1e-16f);
        float hv = h[(size_t)n * 64 + ln];
        asm volatile("" ::: "memory");   // keep read before aliased write
        reinterpret_cast<unsigned short*>(h)[(size_t)n * 128 + ln] = f2bf(hv * inv);
    }
}

// ---------------- aggregate: wave per dst node, 4 edges per dwordx2 gather --
// hh row = 64 bf16 = 32 dwords = 16 uint2, in the first half of a 64-dword
// fp32 row: uint2 row stride is 32 (NOT 16 — round-5 stride lesson).
__global__ __launch_bounds__(256) void aggregate_kernel(
    const int* __restrict__ offsets, const int2* __restrict__ sortedPair,
    const uint2* __restrict__ hhQ, const float* __restrict__ bias,
    float* __restrict__ out, int N)
{
    int gw = (blockIdx.x * blockDim.x + threadIdx.x) >> 6;
    int lane = threadIdx.x & 63;
    if (gw >= N) return;
    int beg = offsets[gw], end = offsets[gw + 1];
    const int quarter = lane >> 4;
    const int cg = lane & 15;
    float a0 = 0.f, a1 = 0.f, a2 = 0.f, a3 = 0.f;
    for (int e0 = beg; e0 < end; e0 += 64) {
        int idx = e0 + lane;
        int2 p = (idx < end) ? sortedPair[idx] : make_int2(0, 0);
        int cnt = min(64, end - e0);
        int j = 0;
        for (; j + 16 <= cnt; j += 16) {
            #pragma unroll
            for (int u = 0; u < 4; ++u) {
                int jj = j + 4 * u + quarter;
                int s = __shfl(p.x, jj);
                float wv = __shfl(__int_as_float(p.y), jj);
                uint2 g = hhQ[(size_t)s * 32 + cg];
                a0 = fmaf(bf2f((unsigned short)(g.x & 0xFFFFu)), wv, a0);
                a1 = fmaf(bf2f((unsigned short)(g.x >> 16)), wv, a1);
                a2 = fmaf(bf2f((unsigned short)(g.y & 0xFFFFu)), wv, a2);
                a3 = fmaf(bf2f((unsigned short)(g.y >> 16)), wv, a3);
            }
        }
        for (; j < cnt; j += 4) {
            int jj = j + quarter;           // <= 63 always (j<=60, quarter<=3)
            int s = __shfl(p.x, jj);
            float wv = __shfl(__int_as_float(p.y), jj);
            uint2 g = hhQ[(size_t)s * 32 + cg];
            a0 = fmaf(bf2f((unsigned short)(g.x & 0xFFFFu)), wv, a0);
            a1 = fmaf(bf2f((unsigned short)(g.x >> 16)), wv, a1);
            a2 = fmaf(bf2f((unsigned short)(g.y & 0xFFFFu)), wv, a2);
            a3 = fmaf(bf2f((unsigned short)(g.y >> 16)), wv, a3);
        }
    }
    a0 += __shfl_xor(a0, 16); a0 += __shfl_xor(a0, 32);
    a1 += __shfl_xor(a1, 16); a1 += __shfl_xor(a1, 32);
    a2 += __shfl_xor(a2, 16); a2 += __shfl_xor(a2, 32);
    a3 += __shfl_xor(a3, 16); a3 += __shfl_xor(a3, 32);
    if (lane < 16) {
        float4 bq = reinterpret_cast<const float4*>(bias)[cg];
        float4 o;
        o.x = a0 + bq.x; o.y = a1 + bq.y; o.z = a2 + bq.z; o.w = a3 + bq.w;
        reinterpret_cast<float4*>(out)[(size_t)gw * 16 + cg] = o;
    }
}

extern "C" void kernel_launch(void* const* d_in, const int* in_sizes, int n_in,
                              void* d_out, int out_size, void* d_ws, size_t ws_size,
                              hipStream_t stream) {
    const float* x    = (const float*)d_in[0];
    const int*   ei   = (const int*)d_in[1];
    // d_in[2] = rank_mapping (unused)
    const float* W1   = (const float*)d_in[3];
    const float* Wp   = (const float*)d_in[4];
    const float* bp   = (const float*)d_in[5];
    const float* bias = (const float*)d_in[6];
    float* out = (float*)d_out;

    const int N = in_sizes[0] / 128;
    const int E = in_sizes[1] / 2;
    const int B = (N + 127) >> 7;        // dst bins of 128 nodes (782)
    const int G = (E + EPB - 1) / EPB;   // pass1/pass2 blocks (306)
    const int NTB = (N + 63) / 64;       // NT blocks, 64 nodes each (1563)

    // workspace (4B units):
    // h[N*64] | a[N] | b[N] | C[G*B] | S[B] | binStart[B+1] | offsets[N+1] |
    // staging[E] int2
    float* h        = (float*)d_ws;
    float* aArr     = h + (size_t)N * 64;
    float* bArr     = aArr + N;
    int*   C        = (int*)(bArr + N);
    int*   S        = C + (size_t)G * B;
    int*   binStart = S + B;
    int*   offsets  = binStart + (B + 1);
    int*   stRaw    = offsets + (N + 1);
    stRaw = (int*)(((uintptr_t)stRaw + 7) & ~(uintptr_t)7);
    int2*  staging  = (int2*)stRaw;

    // pass1 blocks FIRST so they dispatch early and overlap node transform.
    fused_nt_count_kernel<<<G + NTB, 256, 0, stream>>>(
        x, W1, Wp, ei, h, aArr, bArr, C, N, E, G, B);

    colscan_kernel<<<B, 256, 0, stream>>>(C, S, G, B);

    binscan_kernel<<<1, 256, 0, stream>>>(S, binStart, offsets, B, N, E);

    pass2_kernel<<<G, 1024, 0, stream>>>(ei, aArr, bArr, bp, C, binStart,
                                         staging, E, G, B);

    localsort_kernel<<<B, 256, 0, stream>>>(binStart, staging, offsets, h, N);

    aggregate_kernel<<<(N * 64 + 255) / 256, 256, 0, stream>>>(
        offsets, staging, reinterpret_cast<const uint2*>(h), bias, out, N);
}